// Round 1
// 548.253 us; speedup vs baseline: 1.0158x; 1.0158x over previous
//
#include <hip/hip_runtime.h>
#include <hip/hip_bf16.h>
#include <stdint.h>

#define GLOBAL_AS __attribute__((address_space(1)))
#define LDS_AS    __attribute__((address_space(3)))

typedef __attribute__((ext_vector_type(8))) short          short8;
typedef __attribute__((ext_vector_type(4))) float          floatx4;
typedef __attribute__((ext_vector_type(4))) unsigned short ushort4v;

static __device__ __forceinline__ unsigned short f2bf_bits(float f) {
    union { float f; unsigned int u; } v; v.f = f;
    unsigned int r = v.u + 0x7FFFu + ((v.u >> 16) & 1u);   // RNE
    return (unsigned short)(r >> 16);
}

static __device__ __forceinline__ floatx4 mfma16(short8 a, short8 b, floatx4 c) {
    return __builtin_amdgcn_mfma_f32_16x16x32_bf16(a, b, c, 0, 0, 0);
}

// C[M,N] = A[M,K] * B^T  where B is stored row-major [N,K] (gemm_bt pattern).
// EPI: 0 = +bias[row] then bf16 store ; 2 = f32 store ; 3 = f32 partial store at z*pstride
template<int BM, int BN, int BK, int WM, int WN, bool A_F32, bool B_F32, int EPI>
__global__ __launch_bounds__(256, 2)
void gemm_bt(const void* __restrict__ Ap, const void* __restrict__ Bp,
             const float* __restrict__ bias, void* __restrict__ Cp,
             int lda, int ldb, int ldc, int klen, long pstride)
{
    constexpr int NWM = BM / WM;
    constexpr int NWN = BN / WN;
    static_assert(NWM * NWN == 4, "4 waves per block");
    constexpr int FM = WM / 16;
    constexpr int FN = WN / 16;

    __shared__ __align__(16) unsigned short As[BM * BK];
    __shared__ __align__(16) unsigned short Bs[BN * BK];

    const int tid  = threadIdx.x;
    const int lane = tid & 63;
    const int wave = tid >> 6;
    const int wm   = (wave % NWM) * WM;
    const int wn   = (wave / NWM) * WN;
    const int quad = lane >> 4;
    const int l16  = lane & 15;
    const long m0 = (long)blockIdx.x * BM;
    const long n0 = (long)blockIdx.y * BN;
    const long k0 = (long)blockIdx.z * (long)klen;

    floatx4 acc[FM][FN];
#pragma unroll
    for (int i = 0; i < FM; ++i)
#pragma unroll
        for (int j = 0; j < FN; ++j) {
            floatx4 z = {0.f, 0.f, 0.f, 0.f};
            acc[i][j] = z;
        }

    for (int kk = 0; kk < klen; kk += BK) {
        // ---------------- stage A tile [BM x BK] ----------------
        {
            constexpr int CH = BM * BK / 8;   // 8 elems (16B bf16) per chunk
            if constexpr (A_F32) {
                const float* A = (const float*)Ap;
#pragma unroll
                for (int c0 = 0; c0 < CH; c0 += 256) {
                    int c   = c0 + tid;
                    int row = c / (BK / 8);
                    int col = (c % (BK / 8)) * 8;
                    const float* src = A + (m0 + row) * (long)lda + (k0 + kk + col);
                    floatx4 f0 = *(const floatx4*)(src);
                    floatx4 f1 = *(const floatx4*)(src + 4);
                    union { unsigned short u[8]; short8 v; } pk;
                    pk.u[0] = f2bf_bits(f0.x); pk.u[1] = f2bf_bits(f0.y);
                    pk.u[2] = f2bf_bits(f0.z); pk.u[3] = f2bf_bits(f0.w);
                    pk.u[4] = f2bf_bits(f1.x); pk.u[5] = f2bf_bits(f1.y);
                    pk.u[6] = f2bf_bits(f1.z); pk.u[7] = f2bf_bits(f1.w);
                    *(short8*)&As[c * 8] = pk.v;
                }
            } else {
                const unsigned short* A = (const unsigned short*)Ap;
#pragma unroll
                for (int c0 = 0; c0 < CH; c0 += 256) {
                    int c   = c0 + tid;
                    int row = c / (BK / 8);
                    int col = (c % (BK / 8)) * 8;
                    const unsigned short* src = A + (m0 + row) * (long)lda + (k0 + kk + col);
                    __builtin_amdgcn_global_load_lds((const GLOBAL_AS unsigned int*)src,
                                                     (LDS_AS unsigned int*)&As[c * 8],
                                                     16, 0, 0);
                }
            }
        }
        // ---------------- stage B tile [BN x BK] ----------------
        {
            constexpr int CH = BN * BK / 8;
            if constexpr (B_F32) {
                const float* B = (const float*)Bp;
#pragma unroll
                for (int c0 = 0; c0 < CH; c0 += 256) {
                    int c   = c0 + tid;
                    int row = c / (BK / 8);
                    int col = (c % (BK / 8)) * 8;
                    const float* src = B + (n0 + row) * (long)ldb + (k0 + kk + col);
                    floatx4 f0 = *(const floatx4*)(src);
                    floatx4 f1 = *(const floatx4*)(src + 4);
                    union { unsigned short u[8]; short8 v; } pk;
                    pk.u[0] = f2bf_bits(f0.x); pk.u[1] = f2bf_bits(f0.y);
                    pk.u[2] = f2bf_bits(f0.z); pk.u[3] = f2bf_bits(f0.w);
                    pk.u[4] = f2bf_bits(f1.x); pk.u[5] = f2bf_bits(f1.y);
                    pk.u[6] = f2bf_bits(f1.z); pk.u[7] = f2bf_bits(f1.w);
                    *(short8*)&Bs[c * 8] = pk.v;
                }
            } else {
                const unsigned short* B = (const unsigned short*)Bp;
#pragma unroll
                for (int c0 = 0; c0 < CH; c0 += 256) {
                    int c   = c0 + tid;
                    int row = c / (BK / 8);
                    int col = (c % (BK / 8)) * 8;
                    const unsigned short* src = B + (n0 + row) * (long)ldb + (k0 + kk + col);
                    __builtin_amdgcn_global_load_lds((const GLOBAL_AS unsigned int*)src,
                                                     (LDS_AS unsigned int*)&Bs[c * 8],
                                                     16, 0, 0);
                }
            }
        }
        __syncthreads();   // compiler drains vmcnt+lgkmcnt here

        // ---------------- MFMA over the tile ----------------
#pragma unroll
        for (int ks = 0; ks < BK; ks += 32) {
            short8 af[FM], bfr[FN];
#pragma unroll
            for (int i = 0; i < FM; ++i)
                af[i] = *(const short8*)&As[(wm + i * 16 + l16) * BK + ks + quad * 8];
#pragma unroll
            for (int j = 0; j < FN; ++j)
                bfr[j] = *(const short8*)&Bs[(wn + j * 16 + l16) * BK + ks + quad * 8];
#pragma unroll
            for (int i = 0; i < FM; ++i)
#pragma unroll
                for (int j = 0; j < FN; ++j)
                    acc[i][j] = mfma16(af[i], bfr[j], acc[i][j]);
        }
        __syncthreads();
    }

    // ---------------- epilogue ----------------
#pragma unroll
    for (int i = 0; i < FM; ++i)
#pragma unroll
        for (int j = 0; j < FN; ++j)
#pragma unroll
            for (int v = 0; v < 4; ++v) {
                long r = m0 + wm + i * 16 + quad * 4 + v;
                long c = n0 + wn + j * 16 + l16;
                float val = acc[i][j][v];
                if constexpr (EPI == 0) {
                    val += bias[r];
                    ((unsigned short*)Cp)[r * (long)ldc + c] = f2bf_bits(val);
                } else if constexpr (EPI == 2) {
                    ((float*)Cp)[r * (long)ldc + c] = val;
                } else {  // EPI == 3: split-K partial, fp32
                    ((float*)Cp)[(long)blockIdx.z * pstride + r * (long)ldc + c] = val;
                }
            }
}

// Symmetric GEMM: C = A*A^T, A bf16 [8192, klen], C fp32 [8192,8192].
// 1-D triangular grid: block k -> (bi,bj), bi>=bj. Writes tile (bi,bj) and
// its transpose (bj,bi), halving MFMA work (C is symmetric).
template<int BM, int BN, int BK, int WM, int WN>
__global__ __launch_bounds__(256, 2)
void gemm_sym(const unsigned short* __restrict__ A, float* __restrict__ C,
              int ld, int ldc, int klen)
{
    constexpr int NWM = BM / WM;
    constexpr int NWN = BN / WN;
    static_assert(NWM * NWN == 4, "4 waves per block");
    constexpr int FM = WM / 16;
    constexpr int FN = WN / 16;

    __shared__ __align__(16) unsigned short As[BM * BK];
    __shared__ __align__(16) unsigned short Bs[BN * BK];

    // triangular decode: k = bi*(bi+1)/2 + bj, bj <= bi
    const int kblk = blockIdx.x;
    int bi = (int)((sqrtf(8.f * (float)kblk + 1.f) - 1.f) * 0.5f);
    while ((bi + 1) * (bi + 2) / 2 <= kblk) ++bi;
    while (bi * (bi + 1) / 2 > kblk) --bi;
    const int bj = kblk - bi * (bi + 1) / 2;

    const long m0 = (long)bi * BM;
    const long n0 = (long)bj * BN;

    const int tid  = threadIdx.x;
    const int lane = tid & 63;
    const int wave = tid >> 6;
    const int wm   = (wave % NWM) * WM;
    const int wn   = (wave / NWM) * WN;
    const int quad = lane >> 4;
    const int l16  = lane & 15;

    floatx4 acc[FM][FN];
#pragma unroll
    for (int i = 0; i < FM; ++i)
#pragma unroll
        for (int j = 0; j < FN; ++j) {
            floatx4 z = {0.f, 0.f, 0.f, 0.f};
            acc[i][j] = z;
        }

    for (int kk = 0; kk < klen; kk += BK) {
        {
            constexpr int CH = BM * BK / 8;
#pragma unroll
            for (int c0 = 0; c0 < CH; c0 += 256) {
                int c   = c0 + tid;
                int row = c / (BK / 8);
                int col = (c % (BK / 8)) * 8;
                const unsigned short* src = A + (m0 + row) * (long)ld + (kk + col);
                __builtin_amdgcn_global_load_lds((const GLOBAL_AS unsigned int*)src,
                                                 (LDS_AS unsigned int*)&As[c * 8],
                                                 16, 0, 0);
            }
        }
        {
            constexpr int CH = BN * BK / 8;
#pragma unroll
            for (int c0 = 0; c0 < CH; c0 += 256) {
                int c   = c0 + tid;
                int row = c / (BK / 8);
                int col = (c % (BK / 8)) * 8;
                const unsigned short* src = A + (n0 + row) * (long)ld + (kk + col);
                __builtin_amdgcn_global_load_lds((const GLOBAL_AS unsigned int*)src,
                                                 (LDS_AS unsigned int*)&Bs[c * 8],
                                                 16, 0, 0);
            }
        }
        __syncthreads();

#pragma unroll
        for (int ks = 0; ks < BK; ks += 32) {
            short8 af[FM], bfr[FN];
#pragma unroll
            for (int i = 0; i < FM; ++i)
                af[i] = *(const short8*)&As[(wm + i * 16 + l16) * BK + ks + quad * 8];
#pragma unroll
            for (int j = 0; j < FN; ++j)
                bfr[j] = *(const short8*)&Bs[(wn + j * 16 + l16) * BK + ks + quad * 8];
#pragma unroll
            for (int i = 0; i < FM; ++i)
#pragma unroll
                for (int j = 0; j < FN; ++j)
                    acc[i][j] = mfma16(af[i], bfr[j], acc[i][j]);
        }
        __syncthreads();
    }

    // epilogue: write (bi,bj) tile scalar-wise (coalesced across l16), and the
    // mirrored (bj,bi) tile as one 16B floatx4 per lane (4 consecutive rows of
    // the source tile = 4 consecutive cols of the mirror = contiguous floats).
#pragma unroll
    for (int i = 0; i < FM; ++i)
#pragma unroll
        for (int j = 0; j < FN; ++j) {
            const long r0 = m0 + wm + i * 16 + quad * 4;
            const long c  = n0 + wn + j * 16 + l16;
#pragma unroll
            for (int v = 0; v < 4; ++v)
                C[(r0 + v) * (long)ldc + c] = acc[i][j][v];
            if (bi != bj)
                *(floatx4*)&C[c * (long)ldc + r0] = acc[i][j];
        }
}

// Wt[n][k] = bf16(W[k][n]),  W is 256x256 fp32
__global__ void transpose_w_kernel(const float* __restrict__ W, unsigned short* __restrict__ Wt)
{
    int idx = blockIdx.x * 256 + threadIdx.x;   // 65536 total
    int n = idx >> 8;
    int k = idx & 255;
    Wt[n * 256 + k] = f2bf_bits(W[k * 256 + n]);
}

// xbf = bf16(x), 2M elements, 8 per thread
__global__ void cast_x_kernel(const float* __restrict__ x, unsigned short* __restrict__ xbf)
{
    int i = (blockIdx.x * 256 + threadIdx.x) * 8;
    floatx4 a = *(const floatx4*)(x + i);
    floatx4 b = *(const floatx4*)(x + i + 4);
    union { unsigned short u[8]; short8 v; } pk;
    pk.u[0] = f2bf_bits(a.x); pk.u[1] = f2bf_bits(a.y);
    pk.u[2] = f2bf_bits(a.z); pk.u[3] = f2bf_bits(a.w);
    pk.u[4] = f2bf_bits(b.x); pk.u[5] = f2bf_bits(b.y);
    pk.u[6] = f2bf_bits(b.z); pk.u[7] = f2bf_bits(b.w);
    *(short8*)&xbf[i] = pk.v;
}

// h = bf16(relu(sum of nparts partials)),  2M elements, 4 per thread
__global__ void reduce_relu_kernel(const float* __restrict__ parts, long pstride, int nparts,
                                   unsigned short* __restrict__ h)
{
    int i = (blockIdx.x * 256 + threadIdx.x) * 4;
    floatx4 s = *(const floatx4*)(parts + i);
    for (int p = 1; p < nparts; ++p) {
        floatx4 t = *(const floatx4*)(parts + (long)p * pstride + i);
        s.x += t.x; s.y += t.y; s.z += t.z; s.w += t.w;
    }
    ushort4v o;
    o.x = f2bf_bits(fmaxf(s.x, 0.f));
    o.y = f2bf_bits(fmaxf(s.y, 0.f));
    o.z = f2bf_bits(fmaxf(s.z, 0.f));
    o.w = f2bf_bits(fmaxf(s.w, 0.f));
    *(ushort4v*)&h[i] = o;
}

extern "C" void kernel_launch(void* const* d_in, const int* in_sizes, int n_in,
                              void* d_out, int out_size, void* d_ws, size_t ws_size,
                              hipStream_t stream)
{
    const float* x   = (const float*)d_in[0];   // [8192,256]
    const float* adj = (const float*)d_in[1];   // [8192,8192]
    const float* W   = (const float*)d_in[2];   // [256,256]
    const float* b   = (const float*)d_in[3];   // [256]
    float* out = (float*)d_out;                 // [8192,8192]

    char* ws = (char*)d_ws;
    const long PSTRIDE = 8192L * 256L;          // elements per split-K partial

    // Big plan needs: Wt 128KB | xbf 4MB | supT 4MB | h 4MB | parts 32MB = ~44.2MB
    const size_t BIG_NEED = 12713984u + 4u * 8388608u;   // 46,268,416 B
    const bool big = ws_size >= BIG_NEED;

    if (big) {
        unsigned short* Wt   = (unsigned short*)(ws);
        unsigned short* xbf  = (unsigned short*)(ws + 131072);
        unsigned short* supT = (unsigned short*)(ws + 4325376);
        unsigned short* h    = (unsigned short*)(ws + 8519680);
        float*          parts= (float*)         (ws + 12713984);

        // 1) Wt = transpose(bf16(W)); xbf = bf16(x)
        transpose_w_kernel<<<256, 256, 0, stream>>>(W, Wt);
        cast_x_kernel<<<1024, 256, 0, stream>>>(x, xbf);

        // 2) supT[256,8192] = Wt * xbf^T + b[row]   (all-bf16, global_load_lds both sides)
        gemm_bt<32, 256, 64, 32, 64, false, false, 0>
            <<<dim3(8, 32, 1), 256, 0, stream>>>(Wt, xbf, b, supT, 256, 256, 8192, 256, 0);

        // 3) parts[z] = adj * supT^T  (BM=64, split-K=4 -> 512 blocks, 2/CU)
        gemm_bt<64, 256, 64, 64, 64, true, false, 3>
            <<<dim3(128, 1, 4), 256, 0, stream>>>(adj, supT, nullptr, parts,
                                                  8192, 8192, 256, 2048, PSTRIDE);

        // 4) h = bf16(relu(p0+p1+p2+p3))
        reduce_relu_kernel<<<2048, 256, 0, stream>>>(parts, PSTRIDE, 4, h);

        // 5) out = h * h^T, symmetric: lower-triangle blocks only, mirror-write
        gemm_sym<128, 128, 64, 64, 64>
            <<<dim3(2080, 1, 1), 256, 0, stream>>>(h, out, 256, 8192, 256);
    } else {
        // Fallback: previous (known-fitting ~24.2MB) layout; keep symmetric gemm5.
        unsigned short* Wt   = (unsigned short*)(ws);
        unsigned short* supT = (unsigned short*)(ws + 131072);
        unsigned short* h    = (unsigned short*)(ws + 4325376);
        float*          parts= (float*)         (ws + 8519680);

        transpose_w_kernel<<<256, 256, 0, stream>>>(W, Wt);

        gemm_bt<32, 256, 64, 32, 64, false, true, 0>
            <<<dim3(8, 32, 1), 256, 0, stream>>>(Wt, x, b, supT, 256, 256, 8192, 256, 0);

        gemm_bt<32, 256, 64, 32, 64, true, false, 3>
            <<<dim3(256, 1, 2), 256, 0, stream>>>(adj, supT, nullptr, parts,
                                                  8192, 8192, 256, 4096, PSTRIDE);

        reduce_relu_kernel<<<2048, 256, 0, stream>>>(parts, PSTRIDE, 2, h);

        gemm_sym<128, 128, 64, 64, 64>
            <<<dim3(2080, 1, 1), 256, 0, stream>>>(h, out, 256, 8192, 256);
    }
}